// Round 1
// baseline (1423.629 us; speedup 1.0000x reference)
//
#include <hip/hip_runtime.h>
#include <hip/hip_bf16.h>
#include <math.h>

// Problem constants (fixed by setup_inputs)
#define G_NUM   64
#define N_NODES 512
#define K_NN    16
#define TOTAL   (G_NUM * N_NODES)   // 32768
#define E_TOTAL (TOTAL * K_NN)      // 524288
#define D0 4
#define D1 64
#define D2 128
#define D3 256

// ---------------------------------------------------------------------------
// Kernel 1: per-graph Euclidean KNN (k=16, no self-loop, ties -> lower index).
// grid = (G, 4), block = 128 threads; each thread owns one target node.
// Writes edge_index (as float32 values) into the tail of d_out.
// ---------------------------------------------------------------------------
__global__ __launch_bounds__(128) void knn_kernel(const float* __restrict__ loc,
                                                  float* __restrict__ out_ei) {
    __shared__ float posx[N_NODES];
    __shared__ float posy[N_NODES];
    const int g  = blockIdx.x;
    const int t  = threadIdx.x;
    const int n  = blockIdx.y * 128 + t;           // node within graph

    // stage all 512 positions of this graph
    for (int i = t; i < N_NODES; i += 128) {
        const float* row = loc + (size_t)(g * N_NODES + i) * 10;
        posx[i] = row[6];
        posy[i] = row[7];
    }
    __syncthreads();

    const float px = posx[n];
    const float py = posy[n];

    float dist[K_NN];
    int   idx[K_NN];
#pragma unroll
    for (int j = 0; j < K_NN; ++j) { dist[j] = INFINITY; idx[j] = 0; }

    for (int c = 0; c < N_NODES; ++c) {
        if (c == n) continue;                       // bt_self_loop=False
        const float dx = posx[c] - px;
        const float dy = posy[c] - py;
        const float d  = dx * dx + dy * dy;
        if (d < dist[K_NN - 1]) {                   // strict < keeps earlier index on ties
            dist[K_NN - 1] = d;
            idx[K_NN - 1]  = c;
#pragma unroll
            for (int j = K_NN - 1; j > 0; --j) {
                if (dist[j] < dist[j - 1]) {        // strict < : stable like lax.top_k
                    float td = dist[j]; dist[j] = dist[j - 1]; dist[j - 1] = td;
                    int   ti = idx[j];  idx[j]  = idx[j - 1];  idx[j - 1]  = ti;
                }
            }
        }
    }

    const int node  = g * N_NODES + n;
    const size_t eb = (size_t)node * K_NN;
#pragma unroll
    for (int j = 0; j < K_NN; ++j) {
        const int s = g * N_NODES + idx[j];
        out_ei[eb + j]            = (float)s;       // row 0: src
        out_ei[E_TOTAL + eb + j]  = (float)node;    // row 1: tgt
    }
}

// ---------------------------------------------------------------------------
// Kernel 2: fused edge features + 3-layer MLP with ReLU.
// grid = E/64 blocks, 256 threads. 64-edge tile, h1/h2 staged in LDS
// (odd strides 65/129 -> <=2-way bank aliasing = free).
// ---------------------------------------------------------------------------
__global__ __launch_bounds__(256) void mlp_kernel(const float* __restrict__ loc,
                                                  const float* __restrict__ ei_src,
                                                  const float* __restrict__ W1,
                                                  const float* __restrict__ b1,
                                                  const float* __restrict__ W2,
                                                  const float* __restrict__ b2,
                                                  const float* __restrict__ W3,
                                                  const float* __restrict__ b3,
                                                  float* __restrict__ out) {
    __shared__ float feat[64][4];
    __shared__ float h1[64][D1 + 1];   // stride 65
    __shared__ float h2[64][D2 + 1];   // stride 129

    const int t = threadIdx.x;
    const size_t tile_base = (size_t)blockIdx.x * 64;   // first edge of tile

    // ---- Phase 0: raw edge features (threads 0..63, one edge each) ----
    if (t < 64) {
        const size_t e  = tile_base + t;
        const int src   = (int)ei_src[e];               // lossless float->int
        const int tgt   = (int)(e >> 4);                // e / k
        const float* sr = loc + (size_t)src * 10;
        const float* tr = loc + (size_t)tgt * 10;
        feat[t][0] = (sr[6] - tr[6]) / sr[8];
        feat[t][1] = (sr[7] - tr[7]) / sr[9];
        feat[t][2] = logf(sr[4] / tr[4]);
        feat[t][3] = logf(sr[5] / tr[5]);
    }
    __syncthreads();

    // ---- Layer 1: [64 edges] x [4 -> 64] ----
    {
        const int e = t >> 2;          // 0..63
        const int q = t & 3;           // 0..3 -> outputs q*16..q*16+15
        const float f0 = feat[e][0], f1 = feat[e][1], f2 = feat[e][2], f3 = feat[e][3];
#pragma unroll
        for (int m = 0; m < 16; ++m) {
            const int o = q * 16 + m;
            float acc = b1[o];
            acc += f0 * W1[o * 4 + 0];
            acc += f1 * W1[o * 4 + 1];
            acc += f2 * W1[o * 4 + 2];
            acc += f3 * W1[o * 4 + 3];
            h1[e][o] = fmaxf(acc, 0.0f);
        }
    }
    __syncthreads();

    // ---- Layer 2: [64] x [64 -> 128]; thread tile = 4 edges x 8 outputs ----
    {
        const int eg = t & 15;         // edges 4*eg .. 4*eg+3
        const int og = t >> 4;         // outputs og*8 .. og*8+7
        float acc[4][8];
#pragma unroll
        for (int r = 0; r < 4; ++r)
#pragma unroll
            for (int s = 0; s < 8; ++s) acc[r][s] = b2[og * 8 + s];

        for (int j = 0; j < D1; ++j) {
            float hv[4];
#pragma unroll
            for (int r = 0; r < 4; ++r) hv[r] = h1[4 * eg + r][j];
#pragma unroll
            for (int s = 0; s < 8; ++s) {
                const float w = W2[(og * 8 + s) * D1 + j];
#pragma unroll
                for (int r = 0; r < 4; ++r) acc[r][s] += hv[r] * w;
            }
        }
#pragma unroll
        for (int r = 0; r < 4; ++r)
#pragma unroll
            for (int s = 0; s < 8; ++s)
                h2[4 * eg + r][og * 8 + s] = fmaxf(acc[r][s], 0.0f);
    }
    __syncthreads();

    // ---- Layer 3: [64] x [128 -> 256]; thread tile = 4 edges x 16 outputs ----
    {
        const int eg = t & 15;         // edges 4*eg .. 4*eg+3
        const int og = t >> 4;         // outputs og*16 .. og*16+15
        float acc[4][16];
#pragma unroll
        for (int r = 0; r < 4; ++r)
#pragma unroll
            for (int s = 0; s < 16; ++s) acc[r][s] = b3[og * 16 + s];

#pragma unroll 2
        for (int j = 0; j < D2; ++j) {
            float hv[4];
#pragma unroll
            for (int r = 0; r < 4; ++r) hv[r] = h2[4 * eg + r][j];
#pragma unroll
            for (int s = 0; s < 16; ++s) {
                const float w = W3[(og * 16 + s) * D2 + j];
#pragma unroll
                for (int r = 0; r < 4; ++r) acc[r][s] += hv[r] * w;
            }
        }

#pragma unroll
        for (int r = 0; r < 4; ++r) {
            const size_t e = tile_base + 4 * eg + r;
            float4* op = (float4*)(out + e * D3 + og * 16);
#pragma unroll
            for (int v = 0; v < 4; ++v) {
                float4 val;
                val.x = fmaxf(acc[r][v * 4 + 0], 0.0f);
                val.y = fmaxf(acc[r][v * 4 + 1], 0.0f);
                val.z = fmaxf(acc[r][v * 4 + 2], 0.0f);
                val.w = fmaxf(acc[r][v * 4 + 3], 0.0f);
                op[v] = val;
            }
        }
    }
}

extern "C" void kernel_launch(void* const* d_in, const int* in_sizes, int n_in,
                              void* d_out, int out_size, void* d_ws, size_t ws_size,
                              hipStream_t stream) {
    const float* loc = (const float*)d_in[0];
    const float* W1  = (const float*)d_in[1];
    const float* b1  = (const float*)d_in[2];
    const float* W2  = (const float*)d_in[3];
    const float* b2  = (const float*)d_in[4];
    const float* W3  = (const float*)d_in[5];
    const float* b3  = (const float*)d_in[6];
    float* out = (float*)d_out;

    float* out_ei = out + (size_t)E_TOTAL * D3;   // edge_index region (as float values)

    hipLaunchKernelGGL(knn_kernel, dim3(G_NUM, 4), dim3(128), 0, stream,
                       loc, out_ei);
    hipLaunchKernelGGL(mlp_kernel, dim3(E_TOTAL / 64), dim3(256), 0, stream,
                       loc, out_ei, W1, b1, W2, b2, W3, b3, out);
}

// Round 2
// 282.326 us; speedup vs baseline: 5.0425x; 5.0425x over previous
//
#include <hip/hip_runtime.h>
#include <hip/hip_bf16.h>
#include <math.h>

// Problem constants (fixed by setup_inputs)
#define G_NUM   64
#define N_NODES 512
#define K_NN    16
#define TOTAL   (G_NUM * N_NODES)   // 32768
#define E_TOTAL (TOTAL * K_NN)      // 524288
#define D0 4
#define D1 64
#define D2 128
#define D3 256

typedef _Float16 half8 __attribute__((ext_vector_type(8)));
typedef _Float16 half2t __attribute__((ext_vector_type(2)));
typedef float f32x4 __attribute__((ext_vector_type(4)));

// ---------------------------------------------------------------------------
// Kernel 0: prepack W2 [128][64] and W3 [256][128] to f16 in ws.
// Layout stays row-major [out][in]; B-fragment lane reads 8 contiguous f16.
// ---------------------------------------------------------------------------
__global__ __launch_bounds__(256) void prepack_kernel(const float* __restrict__ W2,
                                                      const float* __restrict__ W3,
                                                      _Float16* __restrict__ wsh) {
    const int i = blockIdx.x * 256 + threadIdx.x;
    if (i < D2 * D1) wsh[i] = (_Float16)W2[i];                   // 8192 elems
    const int j = i - D2 * D1;
    if (j >= 0 && j < D3 * D2) wsh[D2 * D1 + j] = (_Float16)W3[j]; // 32768 elems
}

// ---------------------------------------------------------------------------
// Kernel 1: per-graph Euclidean KNN (k=16, no self-loop, ties -> lower index).
// ---------------------------------------------------------------------------
__global__ __launch_bounds__(128) void knn_kernel(const float* __restrict__ loc,
                                                  float* __restrict__ out_ei) {
    __shared__ float posx[N_NODES];
    __shared__ float posy[N_NODES];
    const int g  = blockIdx.x;
    const int t  = threadIdx.x;
    const int n  = blockIdx.y * 128 + t;

    for (int i = t; i < N_NODES; i += 128) {
        const float* row = loc + (size_t)(g * N_NODES + i) * 10;
        posx[i] = row[6];
        posy[i] = row[7];
    }
    __syncthreads();

    const float px = posx[n];
    const float py = posy[n];

    float dist[K_NN];
    int   idx[K_NN];
#pragma unroll
    for (int j = 0; j < K_NN; ++j) { dist[j] = INFINITY; idx[j] = 0; }

    for (int c = 0; c < N_NODES; ++c) {
        if (c == n) continue;
        const float dx = posx[c] - px;
        const float dy = posy[c] - py;
        const float d  = dx * dx + dy * dy;
        if (d < dist[K_NN - 1]) {
            dist[K_NN - 1] = d;
            idx[K_NN - 1]  = c;
#pragma unroll
            for (int j = K_NN - 1; j > 0; --j) {
                if (dist[j] < dist[j - 1]) {
                    float td = dist[j]; dist[j] = dist[j - 1]; dist[j - 1] = td;
                    int   ti = idx[j];  idx[j]  = idx[j - 1];  idx[j - 1]  = ti;
                }
            }
        }
    }

    const int node  = g * N_NODES + n;
    const size_t eb = (size_t)node * K_NN;
#pragma unroll
    for (int j = 0; j < K_NN; ++j) {
        const int s = g * N_NODES + idx[j];
        out_ei[eb + j]            = (float)s;
        out_ei[E_TOTAL + eb + j]  = (float)node;
    }
}

// ---------------------------------------------------------------------------
// Kernel 2: fused features + layer1 (f32 VALU) + layers 2,3 (f16 MFMA).
// Block = 256 threads (4 waves), tile = 64 edges.
// Wave w owns layer-2 cols [w*32,w*32+32) and layer-3 cols [w*64,w*64+64).
// A-fragments from padded LDS (stride 72 / 136 f16 -> conflict-free b128).
// B-fragments streamed from L1-resident f16 weights in ws.
// ---------------------------------------------------------------------------
__global__ __launch_bounds__(256) void mlp_kernel(const float* __restrict__ loc,
                                                  const float* __restrict__ ei_src,
                                                  const float* __restrict__ W1,
                                                  const float* __restrict__ b1,
                                                  const float* __restrict__ b2,
                                                  const float* __restrict__ b3,
                                                  const _Float16* __restrict__ wsh,
                                                  float* __restrict__ out) {
    __shared__ float     feat[64][4];
    __shared__ _Float16  h1s[64][D1 + 8];   // stride 72 f16 = 144 B
    __shared__ _Float16  h2s[64][D2 + 8];   // stride 136 f16 = 272 B

    const int t = threadIdx.x;
    const int w = t >> 6;          // wave 0..3
    const int l = t & 63;          // lane
    const int lr = l & 15;         // row/col-in-tile part of lane
    const int lq = l >> 4;         // quarter-wave
    const size_t tile_base = (size_t)blockIdx.x * 64;

    const _Float16* w2h = wsh;                 // [128][64] f16
    const _Float16* w3h = wsh + D2 * D1;       // [256][128] f16

    // ---- Phase 0: raw edge features (threads 0..63) ----
    if (t < 64) {
        const size_t e  = tile_base + t;
        const int src   = (int)ei_src[e];
        const int tgt   = (int)(e >> 4);
        const float* sr = loc + (size_t)src * 10;
        const float* tr = loc + (size_t)tgt * 10;
        feat[t][0] = (sr[6] - tr[6]) / sr[8];
        feat[t][1] = (sr[7] - tr[7]) / sr[9];
        feat[t][2] = logf(sr[4] / tr[4]);
        feat[t][3] = logf(sr[5] / tr[5]);
    }
    __syncthreads();

    // ---- Layer 1 (f32): edge = l, outputs w*16..w*16+15; W1 rows wave-uniform ----
    {
        const float f0 = feat[l][0], f1 = feat[l][1], f2 = feat[l][2], f3 = feat[l][3];
#pragma unroll
        for (int u = 0; u < 8; ++u) {
            const int o0 = w * 16 + 2 * u;
            float a0 = b1[o0]     + f0 * W1[o0 * 4]     + f1 * W1[o0 * 4 + 1]
                                  + f2 * W1[o0 * 4 + 2] + f3 * W1[o0 * 4 + 3];
            float a1 = b1[o0 + 1] + f0 * W1[o0 * 4 + 4] + f1 * W1[o0 * 4 + 5]
                                  + f2 * W1[o0 * 4 + 6] + f3 * W1[o0 * 4 + 7];
            half2t p;
            p[0] = (_Float16)fmaxf(a0, 0.0f);
            p[1] = (_Float16)fmaxf(a1, 0.0f);
            *(half2t*)&h1s[l][o0] = p;
        }
    }
    __syncthreads();

    // ---- Layer 2 (MFMA f16): M=64, K=64, N=32 per wave (2 n-tiles) ----
    {
        f32x4 acc[4][2];
#pragma unroll
        for (int nn = 0; nn < 2; ++nn) {
            const float bc = b2[w * 32 + nn * 16 + lr];
#pragma unroll
            for (int m = 0; m < 4; ++m)
                acc[m][nn] = (f32x4){bc, bc, bc, bc};
        }
#pragma unroll
        for (int kt = 0; kt < 2; ++kt) {
            half8 bf[2];
#pragma unroll
            for (int nn = 0; nn < 2; ++nn)
                bf[nn] = *(const half8*)(w2h + (w * 32 + nn * 16 + lr) * D1 + kt * 32 + lq * 8);
#pragma unroll
            for (int m = 0; m < 4; ++m) {
                const half8 af = *(const half8*)&h1s[m * 16 + lr][kt * 32 + lq * 8];
#pragma unroll
                for (int nn = 0; nn < 2; ++nn)
                    acc[m][nn] = __builtin_amdgcn_mfma_f32_16x16x32_f16(af, bf[nn], acc[m][nn], 0, 0, 0);
            }
        }
        // write h2 (relu + cvt). C layout: col=lr, row=lq*4+reg
#pragma unroll
        for (int m = 0; m < 4; ++m)
#pragma unroll
            for (int nn = 0; nn < 2; ++nn)
#pragma unroll
                for (int r = 0; r < 4; ++r)
                    h2s[m * 16 + lq * 4 + r][w * 32 + nn * 16 + lr] =
                        (_Float16)fmaxf(acc[m][nn][r], 0.0f);
    }
    __syncthreads();

    // ---- Layer 3 (MFMA f16): M=64, K=128, N=64 per wave (4 n-tiles) ----
    {
        f32x4 acc[4][4];
#pragma unroll
        for (int nn = 0; nn < 4; ++nn) {
            const float bc = b3[w * 64 + nn * 16 + lr];
#pragma unroll
            for (int m = 0; m < 4; ++m)
                acc[m][nn] = (f32x4){bc, bc, bc, bc};
        }
#pragma unroll
        for (int kt = 0; kt < 4; ++kt) {
            half8 bf[4];
#pragma unroll
            for (int nn = 0; nn < 4; ++nn)
                bf[nn] = *(const half8*)(w3h + (w * 64 + nn * 16 + lr) * D2 + kt * 32 + lq * 8);
#pragma unroll
            for (int m = 0; m < 4; ++m) {
                const half8 af = *(const half8*)&h2s[m * 16 + lr][kt * 32 + lq * 8];
#pragma unroll
                for (int nn = 0; nn < 4; ++nn)
                    acc[m][nn] = __builtin_amdgcn_mfma_f32_16x16x32_f16(af, bf[nn], acc[m][nn], 0, 0, 0);
            }
        }
        // store with relu; lane writes out[row=edge][col]
#pragma unroll
        for (int m = 0; m < 4; ++m)
#pragma unroll
            for (int nn = 0; nn < 4; ++nn) {
                const size_t e_base = tile_base + m * 16 + lq * 4;
                const int col = w * 64 + nn * 16 + lr;
#pragma unroll
                for (int r = 0; r < 4; ++r)
                    out[(e_base + r) * D3 + col] = fmaxf(acc[m][nn][r], 0.0f);
            }
    }
}

extern "C" void kernel_launch(void* const* d_in, const int* in_sizes, int n_in,
                              void* d_out, int out_size, void* d_ws, size_t ws_size,
                              hipStream_t stream) {
    const float* loc = (const float*)d_in[0];
    const float* W1  = (const float*)d_in[1];
    const float* b1  = (const float*)d_in[2];
    const float* W2  = (const float*)d_in[3];
    const float* b2  = (const float*)d_in[4];
    const float* W3  = (const float*)d_in[5];
    const float* b3  = (const float*)d_in[6];
    float* out = (float*)d_out;

    float* out_ei = out + (size_t)E_TOTAL * D3;     // edge_index region
    _Float16* wsh = (_Float16*)d_ws;                 // f16 weights (80 KB)

    hipLaunchKernelGGL(prepack_kernel, dim3(160), dim3(256), 0, stream, W2, W3, wsh);
    hipLaunchKernelGGL(knn_kernel, dim3(G_NUM, 4), dim3(128), 0, stream, loc, out_ei);
    hipLaunchKernelGGL(mlp_kernel, dim3(E_TOTAL / 64), dim3(256), 0, stream,
                       loc, out_ei, W1, b1, b2, b3, wsh, out);
}